// Round 1
// baseline (305.457 us; speedup 1.0000x reference)
//
#include <hip/hip_runtime.h>
#include <math.h>

// Problem constants: B=4, T=128, S=512, D=512.
// Outputs: attn_h (4,128,512) then align_vectors (4,128,512), fp32.

// ---------------------------------------------------------------------------
// NT GEMM: C[m,n] = sum_k A[m,k] * W[n,k] + bias[n]
// 64x64 tile, BK=16, 256 threads, 4x4 micro-tile per thread.
// ---------------------------------------------------------------------------
__global__ __launch_bounds__(256) void gemm_nt(
    const float* __restrict__ A, const float* __restrict__ W,
    const float* __restrict__ bias, float* __restrict__ C,
    int K, int ldc)
{
    __shared__ float As[16][64];
    __shared__ float Ws[16][64];
    const int tid = threadIdx.x;
    const int bm = blockIdx.x * 64;
    const int bn = blockIdx.y * 64;
    const int tx = tid & 15;    // n quad index 0..15
    const int ty = tid >> 4;    // m quad index 0..15
    const int lk = tid & 15;    // loader: k within tile
    const int lm = tid >> 4;    // loader: m quad

    float acc[4][4];
    #pragma unroll
    for (int i = 0; i < 4; ++i)
        #pragma unroll
        for (int j = 0; j < 4; ++j) acc[i][j] = 0.f;

    const float* Abase = A + (size_t)bm * K + lk;
    const float* Wbase = W + (size_t)bn * K + lk;

    for (int k0 = 0; k0 < K; k0 += 16) {
        #pragma unroll
        for (int i = 0; i < 4; ++i) {
            int m = lm * 4 + i;
            As[lk][m] = Abase[(size_t)m * K + k0];
            Ws[lk][m] = Wbase[(size_t)m * K + k0];
        }
        __syncthreads();
        #pragma unroll
        for (int k = 0; k < 16; ++k) {
            float4 av = *(const float4*)&As[k][ty * 4];
            float4 wv = *(const float4*)&Ws[k][tx * 4];
            float a0 = av.x, a1 = av.y, a2 = av.z, a3 = av.w;
            float w0 = wv.x, w1 = wv.y, w2 = wv.z, w3 = wv.w;
            acc[0][0] = fmaf(a0, w0, acc[0][0]); acc[0][1] = fmaf(a0, w1, acc[0][1]);
            acc[0][2] = fmaf(a0, w2, acc[0][2]); acc[0][3] = fmaf(a0, w3, acc[0][3]);
            acc[1][0] = fmaf(a1, w0, acc[1][0]); acc[1][1] = fmaf(a1, w1, acc[1][1]);
            acc[1][2] = fmaf(a1, w2, acc[1][2]); acc[1][3] = fmaf(a1, w3, acc[1][3]);
            acc[2][0] = fmaf(a2, w0, acc[2][0]); acc[2][1] = fmaf(a2, w1, acc[2][1]);
            acc[2][2] = fmaf(a2, w2, acc[2][2]); acc[2][3] = fmaf(a2, w3, acc[2][3]);
            acc[3][0] = fmaf(a3, w0, acc[3][0]); acc[3][1] = fmaf(a3, w1, acc[3][1]);
            acc[3][2] = fmaf(a3, w2, acc[3][2]); acc[3][3] = fmaf(a3, w3, acc[3][3]);
        }
        __syncthreads();
    }

    float4 bv = make_float4(0.f, 0.f, 0.f, 0.f);
    if (bias) bv = *(const float4*)&bias[bn + tx * 4];
    #pragma unroll
    for (int i = 0; i < 4; ++i) {
        int m = bm + ty * 4 + i;
        float4 o;
        o.x = acc[i][0] + bv.x;
        o.y = acc[i][1] + bv.y;
        o.z = acc[i][2] + bv.z;
        o.w = acc[i][3] + bv.w;
        *(float4*)&C[(size_t)m * ldc + bn + tx * 4] = o;
    }
}

// ---------------------------------------------------------------------------
// NN GEMM (batched over b): C[m,n] = sum_k A[m,k] * B[k,n]
// ---------------------------------------------------------------------------
__global__ __launch_bounds__(256) void gemm_nn(
    const float* __restrict__ A, const float* __restrict__ B,
    float* __restrict__ C, int K, int lda, int ldb, int ldc,
    int batchA, int batchB, int batchC)
{
    const int b = blockIdx.z;
    A += (size_t)b * batchA;
    B += (size_t)b * batchB;
    C += (size_t)b * batchC;

    __shared__ float As[16][64];
    __shared__ float Bs[16][64];
    const int tid = threadIdx.x;
    const int bm = blockIdx.x * 64;
    const int bn = blockIdx.y * 64;
    const int tx = tid & 15;
    const int ty = tid >> 4;
    const int lk = tid & 15;
    const int lm = tid >> 4;
    const int ln  = tid & 63;   // B loader: n
    const int lkq = tid >> 6;   // B loader: k quad 0..3

    float acc[4][4];
    #pragma unroll
    for (int i = 0; i < 4; ++i)
        #pragma unroll
        for (int j = 0; j < 4; ++j) acc[i][j] = 0.f;

    for (int k0 = 0; k0 < K; k0 += 16) {
        #pragma unroll
        for (int i = 0; i < 4; ++i) {
            int m = lm * 4 + i;
            As[lk][m] = A[(size_t)(bm + m) * lda + k0 + lk];
        }
        #pragma unroll
        for (int i = 0; i < 4; ++i) {
            int k = lkq * 4 + i;
            Bs[k][ln] = B[(size_t)(k0 + k) * ldb + bn + ln];
        }
        __syncthreads();
        #pragma unroll
        for (int k = 0; k < 16; ++k) {
            float4 av = *(const float4*)&As[k][ty * 4];
            float4 wv = *(const float4*)&Bs[k][tx * 4];
            float a0 = av.x, a1 = av.y, a2 = av.z, a3 = av.w;
            float w0 = wv.x, w1 = wv.y, w2 = wv.z, w3 = wv.w;
            acc[0][0] = fmaf(a0, w0, acc[0][0]); acc[0][1] = fmaf(a0, w1, acc[0][1]);
            acc[0][2] = fmaf(a0, w2, acc[0][2]); acc[0][3] = fmaf(a0, w3, acc[0][3]);
            acc[1][0] = fmaf(a1, w0, acc[1][0]); acc[1][1] = fmaf(a1, w1, acc[1][1]);
            acc[1][2] = fmaf(a1, w2, acc[1][2]); acc[1][3] = fmaf(a1, w3, acc[1][3]);
            acc[2][0] = fmaf(a2, w0, acc[2][0]); acc[2][1] = fmaf(a2, w1, acc[2][1]);
            acc[2][2] = fmaf(a2, w2, acc[2][2]); acc[2][3] = fmaf(a2, w3, acc[2][3]);
            acc[3][0] = fmaf(a3, w0, acc[3][0]); acc[3][1] = fmaf(a3, w1, acc[3][1]);
            acc[3][2] = fmaf(a3, w2, acc[3][2]); acc[3][3] = fmaf(a3, w3, acc[3][3]);
        }
        __syncthreads();
    }

    #pragma unroll
    for (int i = 0; i < 4; ++i) {
        int m = bm + ty * 4 + i;
        float4 o;
        o.x = acc[i][0]; o.y = acc[i][1]; o.z = acc[i][2]; o.w = acc[i][3];
        *(float4*)&C[(size_t)m * ldc + bn + tx * 4] = o;
    }
}

// ---------------------------------------------------------------------------
// align[b,t,s] = sum_d v[d] * tanh(wq[b,t,d] + uh[b,s,d])
// Block handles (b, 8 t's, 64 s's). Thread: t = tid>>5, handles s = sb, sb+32.
// ---------------------------------------------------------------------------
__global__ __launch_bounds__(256) void align_kernel(
    const float* __restrict__ wq, const float* __restrict__ uh,
    const float* __restrict__ v, float* __restrict__ out)
{
    __shared__ float wqs[8][512];   // 16 KB
    __shared__ float vsh[512];      //  2 KB
    __shared__ float uhs[64][65];   // 16.6 KB, pad 65 -> conflict-free reads

    const int tid = threadIdx.x;
    const int b  = blockIdx.z;
    const int t0 = blockIdx.y * 8;
    const int s0 = blockIdx.x * 64;

    #pragma unroll
    for (int p = 0; p < 16; ++p) {
        int idx = p * 256 + tid;              // 0..4095
        int t = idx >> 9, d = idx & 511;
        wqs[t][d] = wq[((size_t)(b * 128 + t0 + t) << 9) + d];
    }
    vsh[tid]       = v[tid];
    vsh[tid + 256] = v[tid + 256];

    const int t  = tid >> 5;   // 0..7
    const int sb = tid & 31;   // 0..31
    float acc0 = 0.f, acc1 = 0.f;
    const float* uhbase = uh + ((size_t)(b * 512 + s0) << 9);
    const int ld  = tid & 63;
    const int lsr = tid >> 6;  // 0..3

    for (int k0 = 0; k0 < 512; k0 += 64) {
        #pragma unroll
        for (int p = 0; p < 16; ++p) {
            int s = lsr + (p << 2);
            uhs[s][ld] = uhbase[((size_t)s << 9) + k0 + ld];
        }
        __syncthreads();
        #pragma unroll 4
        for (int k = 0; k < 64; ++k) {
            float vv = vsh[k0 + k];
            float wv = wqs[t][k0 + k];
            float x0 = wv + uhs[sb][k];
            float x1 = wv + uhs[sb + 32][k];
            // tanh(x) = 1 - 2/(exp(2x)+1); saturates correctly at +/-inf
            float e0 = __expf(2.f * x0);
            float e1 = __expf(2.f * x1);
            float th0 = 1.f - 2.f * __builtin_amdgcn_rcpf(e0 + 1.f);
            float th1 = 1.f - 2.f * __builtin_amdgcn_rcpf(e1 + 1.f);
            acc0 = fmaf(vv, th0, acc0);
            acc1 = fmaf(vv, th1, acc1);
        }
        __syncthreads();
    }
    size_t o = ((size_t)(b * 128 + t0 + t) << 9) + s0;
    out[o + sb]      = acc0;
    out[o + sb + 32] = acc1;
}

// ---------------------------------------------------------------------------
// In-place softmax over rows of length 512. One block (256 thr) per row.
// ---------------------------------------------------------------------------
__global__ __launch_bounds__(256) void softmax_512(float* __restrict__ data)
{
    const int row = blockIdx.x;
    float* p = data + ((size_t)row << 9);
    const int tid = threadIdx.x;
    float x0 = p[tid];
    float x1 = p[tid + 256];

    float m = fmaxf(x0, x1);
    #pragma unroll
    for (int off = 32; off > 0; off >>= 1)
        m = fmaxf(m, __shfl_xor(m, off, 64));
    __shared__ float redm[4];
    __shared__ float reds[4];
    const int wave = tid >> 6;
    if ((tid & 63) == 0) redm[wave] = m;
    __syncthreads();
    m = fmaxf(fmaxf(redm[0], redm[1]), fmaxf(redm[2], redm[3]));

    float e0 = __expf(x0 - m);
    float e1 = __expf(x1 - m);
    float s = e0 + e1;
    #pragma unroll
    for (int off = 32; off > 0; off >>= 1)
        s += __shfl_xor(s, off, 64);
    if ((tid & 63) == 0) reds[wave] = s;
    __syncthreads();
    s = reds[0] + reds[1] + reds[2] + reds[3];
    float r = 1.0f / s;
    p[tid]       = e0 * r;
    p[tid + 256] = e1 * r;
}

// ---------------------------------------------------------------------------
// Copy inp (512 rows x 512) into second half of concat rows (stride 1024).
// ---------------------------------------------------------------------------
__global__ __launch_bounds__(256) void copy_inp_to_concat(
    const float* __restrict__ inp, float* __restrict__ concat)
{
    int idx = blockIdx.x * 256 + threadIdx.x;   // 0..65535 (float4 units)
    int row = idx >> 7;
    int c4  = idx & 127;
    float4 val = ((const float4*)inp)[idx];
    ((float4*)concat)[row * 256 + 128 + c4] = val;
}

// ---------------------------------------------------------------------------
extern "C" void kernel_launch(void* const* d_in, const int* in_sizes, int n_in,
                              void* d_out, int out_size, void* d_ws, size_t ws_size,
                              hipStream_t stream)
{
    const float* inp  = (const float*)d_in[0];   // (4,128,512)
    const float* ctx  = (const float*)d_in[1];   // (4,512,512)
    const float* Wq   = (const float*)d_in[2];   // (512,512)
    const float* bq   = (const float*)d_in[3];   // (512)
    const float* Wc   = (const float*)d_in[4];   // (512,512)
    const float* v    = (const float*)d_in[5];   // (512)
    const float* Wout = (const float*)d_in[6];   // (512,1024)
    const float* bout = (const float*)d_in[7];   // (512)

    float* out   = (float*)d_out;
    float* attn  = out;              // 262144 floats
    float* align = out + 262144;     // 262144 floats

    float* ws = (float*)d_ws;
    float* wq = ws;                  // 512*512
    float* uh = ws + 262144;         // 2048*512
    float* cc = ws + 262144 + 1048576;  // 512*1024 concat buffer

    // wq = inp @ Wq^T + bq   (M=512, N=512, K=512)
    gemm_nt<<<dim3(8, 8), 256, 0, stream>>>(inp, Wq, bq, wq, 512, 512);
    // uh = ctx @ Wc^T        (M=2048, N=512, K=512)
    gemm_nt<<<dim3(32, 8), 256, 0, stream>>>(ctx, Wc, nullptr, uh, 512, 512);
    // align scores -> d_out second half
    align_kernel<<<dim3(8, 16, 4), 256, 0, stream>>>(wq, uh, v, align);
    // softmax in place (512 rows)
    softmax_512<<<dim3(512), 256, 0, stream>>>(align);
    // c = align @ ctx, written into concat cols [0,512)  (per-b: 128x512x512)
    gemm_nn<<<dim3(2, 8, 4), 256, 0, stream>>>(align, ctx, cc, 512,
                                               512, 512, 1024,
                                               128 * 512, 512 * 512, 128 * 1024);
    // concat cols [512,1024) = inp
    copy_inp_to_concat<<<dim3(256), 256, 0, stream>>>(inp, cc);
    // attn_h = concat @ Wout^T + bout  (M=512, N=512, K=1024)
    gemm_nt<<<dim3(8, 8), 256, 0, stream>>>(cc, Wout, bout, attn, 1024, 512);
}

// Round 2
// 147.356 us; speedup vs baseline: 2.0729x; 2.0729x over previous
//
#include <hip/hip_runtime.h>
#include <hip/hip_bf16.h>
#include <math.h>

// B=4, T=128, S=512, D=512. Outputs: attn_h (4,128,512) then align (4,128,512), fp32.

typedef __attribute__((ext_vector_type(8))) short short8;
typedef __attribute__((ext_vector_type(4))) float f32x4;
typedef unsigned short ushort_t;

static __device__ __forceinline__ unsigned short f2bf(float x) {
    union { __hip_bfloat16 h; unsigned short u; } c;
    c.h = __float2bfloat16(x);
    return c.u;
}

// ---------------------------------------------------------------------------
// cast_all: fp32 -> bf16 for inp, ctx, Wq, Wc, Wout; inp also into concat
// right half; ctx also transposed into ctxT (for the c-GEMM as NT form).
// Block ranges: [0,256) inp, [256,1280) ctx, [1280,1536) Wq, [1536,1792) Wc,
// [1792,2304) Wout, [2304,3328) ctx transpose (32x32 tiles).
// ---------------------------------------------------------------------------
__global__ __launch_bounds__(256) void cast_all(
    const float* __restrict__ inp, const float* __restrict__ ctx,
    const float* __restrict__ Wq, const float* __restrict__ Wc,
    const float* __restrict__ Wout,
    ushort_t* __restrict__ inp_bf, ushort_t* __restrict__ ctx_bf,
    ushort_t* __restrict__ ctxT_bf, ushort_t* __restrict__ Wq_bf,
    ushort_t* __restrict__ Wc_bf, ushort_t* __restrict__ Wout_bf,
    ushort_t* __restrict__ concat_bf)
{
    __shared__ float tile[32][33];
    const int bid = blockIdx.x, tid = threadIdx.x;

    if (bid < 2304) {
        const float* src; ushort_t* dst; int base; bool is_inp = false;
        if (bid < 256)        { src = inp;  dst = inp_bf;  base = bid * 1024; is_inp = true; }
        else if (bid < 1280)  { src = ctx;  dst = ctx_bf;  base = (bid - 256) * 1024; }
        else if (bid < 1536)  { src = Wq;   dst = Wq_bf;   base = (bid - 1280) * 1024; }
        else if (bid < 1792)  { src = Wc;   dst = Wc_bf;   base = (bid - 1536) * 1024; }
        else                  { src = Wout; dst = Wout_bf; base = (bid - 1792) * 1024; }
        int idx = base + tid * 4;
        float4 v = *(const float4*)(src + idx);
        ushort_t o0 = f2bf(v.x), o1 = f2bf(v.y), o2 = f2bf(v.z), o3 = f2bf(v.w);
        ushort_t* d = dst + idx;
        d[0] = o0; d[1] = o1; d[2] = o2; d[3] = o3;
        if (is_inp) {
            int row = idx >> 9, col = idx & 511;
            ushort_t* c = concat_bf + row * 1024 + 512 + col;
            c[0] = o0; c[1] = o1; c[2] = o2; c[3] = o3;
        }
    } else {
        int r = bid - 2304;                 // 0..1023
        int b = r >> 8;
        int tr = (r >> 4) & 15, tc = r & 15;
        const float* src = ctx + ((size_t)(b * 512 + tr * 32)) * 512 + tc * 32;
        int row8 = tid >> 5, col = tid & 31;
        #pragma unroll
        for (int p = 0; p < 4; ++p) {
            int rr = p * 8 + row8;
            tile[rr][col] = src[rr * 512 + col];
        }
        __syncthreads();
        ushort_t* dst = ctxT_bf + ((size_t)(b * 512 + tc * 32)) * 512 + tr * 32;
        #pragma unroll
        for (int p = 0; p < 4; ++p) {
            int rr = p * 8 + row8;
            dst[rr * 512 + col] = f2bf(tile[col][rr]);
        }
    }
}

// ---------------------------------------------------------------------------
// MFMA NT GEMM: C[m,n] = sum_k A[m,k]*W[n,k] (+bias[n]). A: MxK bf16, W: NxK
// bf16, both row-major (k contiguous). 64x64 tile, BK=32, 256 thr = 4 waves,
// each wave computes a 32x64 strip... no: wave w -> (m half, n half) 32x32,
// 2x2 MFMA 16x16x32 per K-step. LDS rows padded to 40 bf16 (80B, 16B-aligned,
// <=2-way bank aliasing on b128 = free).
// ---------------------------------------------------------------------------
template<bool OUT_BF16>
__global__ __launch_bounds__(256) void mfma_gemm_nt(
    const ushort_t* __restrict__ A, const ushort_t* __restrict__ W,
    const float* __restrict__ bias, void* __restrict__ Cv,
    int K, int lda, int ldw, int ldc,
    long batchA, long batchW, long batchC)
{
    const int b = blockIdx.z;
    A += (size_t)b * batchA;
    W += (size_t)b * batchW;

    __shared__ ushort_t As[64 * 40];
    __shared__ ushort_t Ws[64 * 40];

    const int tid = threadIdx.x;
    const int bm = blockIdx.x * 64, bn = blockIdx.y * 64;
    const int wave = tid >> 6, lane = tid & 63;
    const int mh = (wave & 1) * 32, nh = (wave >> 1) * 32;
    const int quad = lane >> 4, l16 = lane & 15;

    // staging: thread -> (row 0..63, k-chunk 0..3), 8 bf16 = 16B each
    const int srow = tid >> 2, schunk = tid & 3;
    const ushort_t* Ag = A + (size_t)(bm + srow) * lda + schunk * 8;
    const ushort_t* Wg = W + (size_t)(bn + srow) * ldw + schunk * 8;
    int4* AsW = (int4*)&As[srow * 40 + schunk * 8];
    int4* WsW = (int4*)&Ws[srow * 40 + schunk * 8];

    // fragment read pointers (constant across K loop)
    const short8* a0p = (const short8*)&As[(mh + l16) * 40 + quad * 8];
    const short8* a1p = (const short8*)&As[(mh + 16 + l16) * 40 + quad * 8];
    const short8* b0p = (const short8*)&Ws[(nh + l16) * 40 + quad * 8];
    const short8* b1p = (const short8*)&Ws[(nh + 16 + l16) * 40 + quad * 8];

    f32x4 acc00 = {0.f, 0.f, 0.f, 0.f}, acc01 = acc00, acc10 = acc00, acc11 = acc00;

    int4 av = *(const int4*)Ag;
    int4 wv = *(const int4*)Wg;
    for (int k0 = 0; k0 < K; k0 += 32) {
        int4 a_cur = av, w_cur = wv;
        if (k0 + 32 < K) {
            av = *(const int4*)(Ag + k0 + 32);
            wv = *(const int4*)(Wg + k0 + 32);
        }
        __syncthreads();            // previous iteration's frag reads done
        *AsW = a_cur;
        *WsW = w_cur;
        __syncthreads();
        short8 a0 = *a0p, a1 = *a1p, b0 = *b0p, b1 = *b1p;
        acc00 = __builtin_amdgcn_mfma_f32_16x16x32_bf16(a0, b0, acc00, 0, 0, 0);
        acc01 = __builtin_amdgcn_mfma_f32_16x16x32_bf16(a0, b1, acc01, 0, 0, 0);
        acc10 = __builtin_amdgcn_mfma_f32_16x16x32_bf16(a1, b0, acc10, 0, 0, 0);
        acc11 = __builtin_amdgcn_mfma_f32_16x16x32_bf16(a1, b1, acc11, 0, 0, 0);
    }

    const int col0 = bn + nh + l16;
    const int col1 = col0 + 16;
    float bias0 = bias ? bias[col0] : 0.f;
    float bias1 = bias ? bias[col1] : 0.f;

    f32x4 accs[2][2] = {{acc00, acc01}, {acc10, acc11}};
    #pragma unroll
    for (int mt = 0; mt < 2; ++mt) {
        #pragma unroll
        for (int r = 0; r < 4; ++r) {
            size_t row = (size_t)(bm + mh + mt * 16 + quad * 4 + r) + (size_t)b * 0;
            size_t rowoff = ((size_t)b * batchC) + (size_t)(bm + mh + mt * 16 + quad * 4 + r) * ldc;
            float v0 = accs[mt][0][r] + bias0;
            float v1 = accs[mt][1][r] + bias1;
            if (OUT_BF16) {
                ushort_t* C = (ushort_t*)Cv;
                C[rowoff + col0] = f2bf(v0);
                C[rowoff + col1] = f2bf(v1);
            } else {
                float* C = (float*)Cv;
                C[rowoff + col0] = v0;
                C[rowoff + col1] = v1;
            }
        }
    }
}

// ---------------------------------------------------------------------------
// align[b,t,s] = sum_d v[d]*tanh(wq[b,t,d] + uh[b,s,d])
// k across lanes, coalesced global reads, no LDS. Block = 4 waves; wave w
// handles t = t0 + 2w .. +1, s = s0..s0+7. Shuffle-reduce at the end.
// Grid: (S/8=64, T/8=16, B=4) = 4096 blocks.
// ---------------------------------------------------------------------------
__global__ __launch_bounds__(256) void align_kernel(
    const float* __restrict__ wq, const float* __restrict__ uh,
    const float* __restrict__ v, float* __restrict__ out)
{
    const int lane = threadIdx.x & 63, wave = threadIdx.x >> 6;
    const int b = blockIdx.z;
    const int t0 = blockIdx.y * 8 + wave * 2;
    const int s0 = blockIdx.x * 8;

    const float* wq0 = wq + (((size_t)(b * 128 + t0)) << 9);
    const float* wq1 = wq0 + 512;
    const float* uhb = uh + (((size_t)(b * 512 + s0)) << 9);

    float acc0[8], acc1[8];
    #pragma unroll
    for (int j = 0; j < 8; ++j) { acc0[j] = 0.f; acc1[j] = 0.f; }

    for (int k0 = 0; k0 < 512; k0 += 64) {
        float vk = v[k0 + lane];
        float w0 = wq0[k0 + lane];
        float w1 = wq1[k0 + lane];
        #pragma unroll
        for (int j = 0; j < 8; ++j) {
            float u = uhb[((size_t)j << 9) + k0 + lane];
            float x0 = w0 + u, x1 = w1 + u;
            float e0 = __expf(2.f * x0);
            float e1 = __expf(2.f * x1);
            float th0 = 1.f - 2.f * __builtin_amdgcn_rcpf(e0 + 1.f);
            float th1 = 1.f - 2.f * __builtin_amdgcn_rcpf(e1 + 1.f);
            acc0[j] = fmaf(vk, th0, acc0[j]);
            acc1[j] = fmaf(vk, th1, acc1[j]);
        }
    }

    float r0 = 0.f, r1 = 0.f;
    #pragma unroll
    for (int j = 0; j < 8; ++j) {
        float a = acc0[j], c = acc1[j];
        #pragma unroll
        for (int off = 32; off; off >>= 1) {
            a += __shfl_xor(a, off, 64);
            c += __shfl_xor(c, off, 64);
        }
        if (lane == j) { r0 = a; r1 = c; }
    }
    if (lane < 8) {
        size_t o = (((size_t)(b * 128 + t0)) << 9) + s0 + lane;
        out[o] = r0;
        out[o + 512] = r1;
    }
}

// ---------------------------------------------------------------------------
// softmax over rows of 512 (in place, fp32) + bf16 copy for the c-GEMM.
// ---------------------------------------------------------------------------
__global__ __launch_bounds__(256) void softmax_512(
    float* __restrict__ data, ushort_t* __restrict__ pbf)
{
    const int row = blockIdx.x;
    float* p = data + ((size_t)row << 9);
    ushort_t* q = pbf + ((size_t)row << 9);
    const int tid = threadIdx.x;
    float x0 = p[tid];
    float x1 = p[tid + 256];

    float m = fmaxf(x0, x1);
    #pragma unroll
    for (int off = 32; off > 0; off >>= 1)
        m = fmaxf(m, __shfl_xor(m, off, 64));
    __shared__ float redm[4];
    __shared__ float reds[4];
    const int wave = tid >> 6;
    if ((tid & 63) == 0) redm[wave] = m;
    __syncthreads();
    m = fmaxf(fmaxf(redm[0], redm[1]), fmaxf(redm[2], redm[3]));

    float e0 = __expf(x0 - m);
    float e1 = __expf(x1 - m);
    float s = e0 + e1;
    #pragma unroll
    for (int off = 32; off > 0; off >>= 1)
        s += __shfl_xor(s, off, 64);
    if ((tid & 63) == 0) reds[wave] = s;
    __syncthreads();
    s = reds[0] + reds[1] + reds[2] + reds[3];
    float r = 1.0f / s;
    float p0 = e0 * r, p1 = e1 * r;
    p[tid] = p0;
    p[tid + 256] = p1;
    q[tid] = f2bf(p0);
    q[tid + 256] = f2bf(p1);
}

// ---------------------------------------------------------------------------
extern "C" void kernel_launch(void* const* d_in, const int* in_sizes, int n_in,
                              void* d_out, int out_size, void* d_ws, size_t ws_size,
                              hipStream_t stream)
{
    const float* inp  = (const float*)d_in[0];   // (4,128,512)
    const float* ctx  = (const float*)d_in[1];   // (4,512,512)
    const float* Wq   = (const float*)d_in[2];   // (512,512)
    const float* bq   = (const float*)d_in[3];   // (512)
    const float* Wc   = (const float*)d_in[4];   // (512,512)
    const float* v    = (const float*)d_in[5];   // (512)
    const float* Wout = (const float*)d_in[6];   // (512,1024)
    const float* bout = (const float*)d_in[7];   // (512)

    float* out   = (float*)d_out;
    float* attn  = out;              // 262144 floats
    float* align = out + 262144;     // 262144 floats

    float* ws   = (float*)d_ws;
    float* wq_f = ws;                          // 262144 f  (1 MB)
    float* uh_f = ws + 262144;                 // 1048576 f (4 MB)
    ushort_t* bf = (ushort_t*)(ws + 262144 + 1048576);
    ushort_t* inp_bf    = bf;                  // 262144
    ushort_t* ctx_bf    = inp_bf + 262144;     // 1048576
    ushort_t* ctxT_bf   = ctx_bf + 1048576;    // 1048576
    ushort_t* Wq_bf     = ctxT_bf + 1048576;   // 262144
    ushort_t* Wc_bf     = Wq_bf + 262144;      // 262144
    ushort_t* Wout_bf   = Wc_bf + 262144;      // 524288
    ushort_t* concat_bf = Wout_bf + 524288;    // 524288 (rows 512 x 1024)
    ushort_t* P_bf      = concat_bf + 524288;  // 262144

    cast_all<<<dim3(3328), 256, 0, stream>>>(inp, ctx, Wq, Wc, Wout,
        inp_bf, ctx_bf, ctxT_bf, Wq_bf, Wc_bf, Wout_bf, concat_bf);

    // wq = inp @ Wq^T + bq  (M=512,N=512,K=512)
    mfma_gemm_nt<false><<<dim3(8, 8, 1), 256, 0, stream>>>(
        inp_bf, Wq_bf, bq, wq_f, 512, 512, 512, 512, 0, 0, 0);

    // uh = ctx @ Wc^T  (M=2048,N=512,K=512)
    mfma_gemm_nt<false><<<dim3(32, 8, 1), 256, 0, stream>>>(
        ctx_bf, Wc_bf, nullptr, uh_f, 512, 512, 512, 512, 0, 0, 0);

    // align scores
    align_kernel<<<dim3(64, 16, 4), 256, 0, stream>>>(wq_f, uh_f, v, align);

    // softmax (fp32 in d_out) + bf16 P
    softmax_512<<<dim3(512), 256, 0, stream>>>(align, P_bf);

    // c = P @ ctx = P @ (ctxT)^T : per-batch M=128,N=512,K=512 -> concat left
    mfma_gemm_nt<true><<<dim3(2, 8, 4), 256, 0, stream>>>(
        P_bf, ctxT_bf, nullptr, concat_bf, 512, 512, 512, 1024,
        128 * 512, 512 * 512, 128 * 1024);

    // attn_h = concat @ Wout^T + bout  (M=512,N=512,K=1024)
    mfma_gemm_nt<false><<<dim3(8, 8, 1), 256, 0, stream>>>(
        concat_bf, Wout_bf, bout, attn, 1024, 1024, 1024, 512, 0, 0, 0);
}

// Round 4
// 124.507 us; speedup vs baseline: 2.4533x; 1.1835x over previous
//
#include <hip/hip_runtime.h>
#include <hip/hip_bf16.h>
#include <math.h>

// B=4, T=128, S=512, D=512. Outputs: attn_h (4,128,512) then align (4,128,512), fp32.

typedef __attribute__((ext_vector_type(8))) short short8;
typedef __attribute__((ext_vector_type(4))) float f32x4;
typedef unsigned short ushort_t;

static __device__ __forceinline__ unsigned short f2bf(float x) {
    union { __hip_bfloat16 h; unsigned short u; } c;
    c.h = __float2bfloat16(x);
    return c.u;
}
static __device__ __forceinline__ int bf2x(float lo, float hi) {
    return (int)(((unsigned)f2bf(hi) << 16) | (unsigned)f2bf(lo));
}

// Load 16 contiguous elements (fp32->cvt or bf16 direct) as 16 bf16 in 2 int4.
template<bool BF>
static __device__ __forceinline__ void load16(const void* base, size_t elemoff,
                                              int4& r0, int4& r1) {
    if (BF) {
        const int4* p = (const int4*)((const ushort_t*)base + elemoff);
        r0 = p[0]; r1 = p[1];
    } else {
        const float4* p = (const float4*)((const float*)base + elemoff);
        float4 a = p[0], b = p[1], c = p[2], d = p[3];
        r0.x = bf2x(a.x, a.y); r0.y = bf2x(a.z, a.w);
        r0.z = bf2x(b.x, b.y); r0.w = bf2x(b.z, b.w);
        r1.x = bf2x(c.x, c.y); r1.y = bf2x(c.z, c.w);
        r1.z = bf2x(d.x, d.y); r1.w = bf2x(d.z, d.w);
    }
}

// ---------------------------------------------------------------------------
// MFMA NT GEMM body: C[m,n] = sum_k A[m,k]*W[n,k] (+bias). 64x64 tile, BK=64,
// 256 thr = 4 waves (2x2 wave grid of 32x32), 2x2 MFMA 16x16x32 per 32-K.
// LDS rows padded to 72 bf16 -> <=2-way bank aliasing on b128 reads (free).
// EPI: 0 = fp32 (+bias); 1 = fp32 exp(2*(x+bias)); 2 = bf16; 3 = fp32 x+partial.
// ---------------------------------------------------------------------------
template<bool A_BF, bool W_BF, int EPI>
static __device__ __forceinline__ void gemm_body(
    ushort_t* As, ushort_t* Ws,
    const void* A, const void* W, const float* bias, const float* partial,
    void* Cv, int K, int lda, int ldw, int ldc, int bm, int bn)
{
    const int tid = threadIdx.x;
    const int wave = tid >> 6, lane = tid & 63;
    const int mh = (wave & 1) * 32, nh = (wave >> 1) * 32;
    const int quad = lane >> 4, l16 = lane & 15;
    const int srow = tid >> 2, schunk = tid & 3;

    const size_t aoff = (size_t)(bm + srow) * lda + schunk * 16;
    const size_t woff = (size_t)(bn + srow) * ldw + schunk * 16;
    int4* AsW = (int4*)&As[srow * 72 + schunk * 16];
    int4* WsW = (int4*)&Ws[srow * 72 + schunk * 16];

    f32x4 acc00 = {0.f, 0.f, 0.f, 0.f}, acc01 = acc00, acc10 = acc00, acc11 = acc00;

    int4 a0r, a1r, w0r, w1r;
    load16<A_BF>(A, aoff, a0r, a1r);
    load16<W_BF>(W, woff, w0r, w1r);

    for (int k0 = 0; k0 < K; k0 += 64) {
        AsW[0] = a0r; AsW[1] = a1r;
        WsW[0] = w0r; WsW[1] = w1r;
        __syncthreads();
        if (k0 + 64 < K) {
            load16<A_BF>(A, aoff + k0 + 64, a0r, a1r);
            load16<W_BF>(W, woff + k0 + 64, w0r, w1r);
        }
        #pragma unroll
        for (int kk = 0; kk < 64; kk += 32) {
            short8 a0 = *(const short8*)&As[(mh + l16) * 72 + kk + quad * 8];
            short8 a1 = *(const short8*)&As[(mh + 16 + l16) * 72 + kk + quad * 8];
            short8 b0 = *(const short8*)&Ws[(nh + l16) * 72 + kk + quad * 8];
            short8 b1 = *(const short8*)&Ws[(nh + 16 + l16) * 72 + kk + quad * 8];
            acc00 = __builtin_amdgcn_mfma_f32_16x16x32_bf16(a0, b0, acc00, 0, 0, 0);
            acc01 = __builtin_amdgcn_mfma_f32_16x16x32_bf16(a0, b1, acc01, 0, 0, 0);
            acc10 = __builtin_amdgcn_mfma_f32_16x16x32_bf16(a1, b0, acc10, 0, 0, 0);
            acc11 = __builtin_amdgcn_mfma_f32_16x16x32_bf16(a1, b1, acc11, 0, 0, 0);
        }
        __syncthreads();
    }

    const int col0 = bn + nh + l16;
    const int col1 = col0 + 16;
    float bias0 = bias ? bias[col0] : 0.f;
    float bias1 = bias ? bias[col1] : 0.f;

    f32x4 accs[2][2] = {{acc00, acc01}, {acc10, acc11}};
    #pragma unroll
    for (int mt = 0; mt < 2; ++mt) {
        #pragma unroll
        for (int r = 0; r < 4; ++r) {
            int row = bm + mh + mt * 16 + quad * 4 + r;
            size_t rowoff = (size_t)row * ldc;
            float v0 = accs[mt][0][r] + bias0;
            float v1 = accs[mt][1][r] + bias1;
            if (EPI == 1) { v0 = __expf(2.f * v0); v1 = __expf(2.f * v1); }
            if (EPI == 3) { v0 += partial[rowoff + col0]; v1 += partial[rowoff + col1]; }
            if (EPI == 2) {
                ushort_t* C = (ushort_t*)Cv;
                C[rowoff + col0] = f2bf(v0);
                C[rowoff + col1] = f2bf(v1);
            } else {
                float* C = (float*)Cv;
                C[rowoff + col0] = v0;
                C[rowoff + col1] = v1;
            }
        }
    }
}

// ---------------------------------------------------------------------------
// Fused front: [0,64) Ew = exp(2*(inp@Wq^T+bq)); [64,320) Eu = exp(2*(ctx@Wc^T));
// [320,384) Y0 = inp@WR^T + bout; [384,1408) ctx -> ctxT bf16 (32x32 tiles).
// ---------------------------------------------------------------------------
__global__ __launch_bounds__(256) void fused_front(
    const float* __restrict__ inp, const float* __restrict__ ctx,
    const float* __restrict__ Wq, const float* __restrict__ bq,
    const float* __restrict__ Wc, const float* __restrict__ Wout,
    const float* __restrict__ bout,
    float* __restrict__ Ew, float* __restrict__ Eu, float* __restrict__ Y0,
    ushort_t* __restrict__ ctxT)
{
    __shared__ ushort_t As[64 * 72];
    __shared__ ushort_t Ws[64 * 72];
    __shared__ float tile[32][33];
    const int bid = blockIdx.x, tid = threadIdx.x;

    if (bid < 64) {
        gemm_body<false, false, 1>(As, Ws, inp, Wq, bq, nullptr, Ew,
                                   512, 512, 512, 512, (bid & 7) * 64, (bid >> 3) * 64);
    } else if (bid < 320) {
        int i = bid - 64;
        gemm_body<false, false, 1>(As, Ws, ctx, Wc, nullptr, nullptr, Eu,
                                   512, 512, 512, 512, (i & 31) * 64, (i >> 5) * 64);
    } else if (bid < 384) {
        int i = bid - 320;
        gemm_body<false, false, 0>(As, Ws, inp, Wout + 512, bout, nullptr, Y0,
                                   512, 512, 1024, 512, (i & 7) * 64, (i >> 3) * 64);
    } else {
        int r = bid - 384;                  // 0..1023
        int b = r >> 8;
        int tr = (r >> 4) & 15, tc = r & 15;
        const float* src = ctx + ((size_t)(b * 512 + tr * 32)) * 512 + tc * 32;
        int row8 = tid >> 5, col = tid & 31;
        #pragma unroll
        for (int p = 0; p < 4; ++p) {
            int rr = p * 8 + row8;
            tile[rr][col] = src[rr * 512 + col];
        }
        __syncthreads();
        ushort_t* dst = ctxT + ((size_t)(b * 512 + tc * 32)) * 512 + tr * 32;
        #pragma unroll
        for (int p = 0; p < 4; ++p) {
            int rr = p * 8 + row8;
            dst[rr * 512 + col] = f2bf(tile[col][rr]);
        }
    }
}

// ---------------------------------------------------------------------------
// align[b,t,s] = V - 2*sum_d v[d] / (1 + Ew[b,t,d]*Eu[b,s,d]),  V = sum_d v[d]
// (== sum_d v[d]*tanh(wq+uh)). 2 VALU + 1 rcp per element.
// Wave w: t = t0+2w..+1, s = s0..s0+7. Grid (64, 16, 4).
// ---------------------------------------------------------------------------
__global__ __launch_bounds__(256) void align_kernel(
    const float* __restrict__ Ew, const float* __restrict__ Eu,
    const float* __restrict__ v, float* __restrict__ out)
{
    const int lane = threadIdx.x & 63, wave = threadIdx.x >> 6;
    const int b = blockIdx.z;
    const int t0 = blockIdx.y * 8 + wave * 2;
    const int s0 = blockIdx.x * 8;

    const float* w0p = Ew + (((size_t)(b * 128 + t0)) << 9);
    const float* w1p = w0p + 512;
    const float* up  = Eu + (((size_t)(b * 512 + s0)) << 9);

    float acc0[8], acc1[8];
    #pragma unroll
    for (int j = 0; j < 8; ++j) { acc0[j] = 0.f; acc1[j] = 0.f; }
    float vsum = 0.f;

    for (int k0 = 0; k0 < 512; k0 += 64) {
        float vk = v[k0 + lane];
        vsum += vk;
        float w0 = w0p[k0 + lane];
        float w1 = w1p[k0 + lane];
        #pragma unroll
        for (int j = 0; j < 8; ++j) {
            float u = up[((size_t)j << 9) + k0 + lane];
            float d0 = fmaf(w0, u, 1.f);
            float d1 = fmaf(w1, u, 1.f);
            float r0 = __builtin_amdgcn_rcpf(d0);
            float r1 = __builtin_amdgcn_rcpf(d1);
            acc0[j] = fmaf(vk, r0, acc0[j]);
            acc1[j] = fmaf(vk, r1, acc1[j]);
        }
    }

    float V = vsum;
    #pragma unroll
    for (int off = 32; off; off >>= 1) V += __shfl_xor(V, off, 64);

    float r0 = 0.f, r1 = 0.f;
    #pragma unroll
    for (int j = 0; j < 8; ++j) {
        float a = acc0[j], c = acc1[j];
        #pragma unroll
        for (int off = 32; off; off >>= 1) {
            a += __shfl_xor(a, off, 64);
            c += __shfl_xor(c, off, 64);
        }
        if (lane == j) { r0 = fmaf(-2.f, a, V); r1 = fmaf(-2.f, c, V); }
    }
    if (lane < 8) {
        size_t o = (((size_t)(b * 128 + t0)) << 9) + s0 + lane;
        out[o] = r0;
        out[o + 512] = r1;
    }
}

// ---------------------------------------------------------------------------
// softmax over rows of 512 (in place fp32) + bf16 copy for the c-GEMM.
// ---------------------------------------------------------------------------
__global__ __launch_bounds__(256) void softmax_512(
    float* __restrict__ data, ushort_t* __restrict__ pbf)
{
    const int row = blockIdx.x;
    float* p = data + ((size_t)row << 9);
    ushort_t* q = pbf + ((size_t)row << 9);
    const int tid = threadIdx.x;
    float x0 = p[tid];
    float x1 = p[tid + 256];

    float m = fmaxf(x0, x1);
    #pragma unroll
    for (int off = 32; off > 0; off >>= 1)
        m = fmaxf(m, __shfl_xor(m, off, 64));
    __shared__ float redm[4];
    __shared__ float reds[4];
    const int wave = tid >> 6;
    if ((tid & 63) == 0) redm[wave] = m;
    __syncthreads();
    m = fmaxf(fmaxf(redm[0], redm[1]), fmaxf(redm[2], redm[3]));

    float e0 = __expf(x0 - m);
    float e1 = __expf(x1 - m);
    float s = e0 + e1;
    #pragma unroll
    for (int off = 32; off > 0; off >>= 1)
        s += __shfl_xor(s, off, 64);
    if ((tid & 63) == 0) reds[wave] = s;
    __syncthreads();
    s = reds[0] + reds[1] + reds[2] + reds[3];
    float r = 1.0f / s;
    float p0 = e0 * r, p1 = e1 * r;
    p[tid] = p0;
    p[tid + 256] = p1;
    q[tid] = f2bf(p0);
    q[tid + 256] = f2bf(p1);
}

// ---------------------------------------------------------------------------
// c = P @ ctx (via ctxT, NT form), bf16 out. Per-batch M=128,N=512,K=512.
// ---------------------------------------------------------------------------
__global__ __launch_bounds__(256) void gemm_c(
    const ushort_t* __restrict__ P, const ushort_t* __restrict__ ctxT,
    ushort_t* __restrict__ cbf)
{
    __shared__ ushort_t As[64 * 72];
    __shared__ ushort_t Ws[64 * 72];
    const int b = blockIdx.z;
    gemm_body<true, true, 2>(As, Ws, P + (size_t)b * 65536, ctxT + (size_t)b * 262144,
                             nullptr, nullptr, cbf + (size_t)b * 65536,
                             512, 512, 512, 512, blockIdx.x * 64, blockIdx.y * 64);
}

// ---------------------------------------------------------------------------
// attn = c @ WL^T + Y0.  (WL = Wout[:, :512], lda 1024.)
// NOTE: Y0 already contains bout — bias must be nullptr here (R3 bug: it was
// passed again, double-adding bout -> absmax 0.17 fail).
// ---------------------------------------------------------------------------
__global__ __launch_bounds__(256) void gemm_out(
    const ushort_t* __restrict__ cbf, const float* __restrict__ Wout,
    const float* __restrict__ Y0, float* __restrict__ attn)
{
    __shared__ ushort_t As[64 * 72];
    __shared__ ushort_t Ws[64 * 72];
    gemm_body<true, false, 3>(As, Ws, cbf, Wout, nullptr, Y0, attn,
                              512, 512, 1024, 512, blockIdx.x * 64, blockIdx.y * 64);
}

// ---------------------------------------------------------------------------
extern "C" void kernel_launch(void* const* d_in, const int* in_sizes, int n_in,
                              void* d_out, int out_size, void* d_ws, size_t ws_size,
                              hipStream_t stream)
{
    const float* inp  = (const float*)d_in[0];   // (4,128,512)
    const float* ctx  = (const float*)d_in[1];   // (4,512,512)
    const float* Wq   = (const float*)d_in[2];   // (512,512)
    const float* bq   = (const float*)d_in[3];   // (512)
    const float* Wc   = (const float*)d_in[4];   // (512,512)
    const float* v    = (const float*)d_in[5];   // (512)
    const float* Wout = (const float*)d_in[6];   // (512,1024)
    const float* bout = (const float*)d_in[7];   // (512)

    float* out   = (float*)d_out;
    float* attn  = out;              // 262144 floats
    float* align = out + 262144;     // 262144 floats

    float* ws = (float*)d_ws;
    float* Ew = ws;                           // 262144 f
    float* Eu = ws + 262144;                  // 1048576 f
    float* Y0 = ws + 1310720;                 // 262144 f
    ushort_t* ub   = (ushort_t*)(ws + 1572864);
    ushort_t* ctxT = ub;                      // 1048576 u16
    ushort_t* P_bf = ub + 1048576;            // 262144 u16
    ushort_t* c_bf = P_bf + 262144;           // 262144 u16

    fused_front<<<dim3(1408), 256, 0, stream>>>(inp, ctx, Wq, bq, Wc, Wout, bout,
                                                Ew, Eu, Y0, ctxT);
    align_kernel<<<dim3(64, 16, 4), 256, 0, stream>>>(Ew, Eu, v, align);
    softmax_512<<<dim3(512), 256, 0, stream>>>(align, P_bf);
    gemm_c<<<dim3(2, 8, 4), 256, 0, stream>>>(P_bf, ctxT, c_bf);
    gemm_out<<<dim3(8, 8), 256, 0, stream>>>(c_bf, Wout, Y0, attn);
}